// Round 6
// baseline (258.449 us; speedup 1.0000x reference)
//
#include <hip/hip_runtime.h>
#include <hip/hip_bf16.h>
#include <math.h>

constexpr int cB = 8, cNQ = 300, cC = 256, cH = 64, cW = 64, cHEADS = 8, cHD = 32;
constexpr int cHW = cH * cW;
constexpr int cM = cB * cNQ;  // 2400
constexpr float cSCALE = 0.1767766952966369f; // 32^-0.5

typedef __bf16 bf16_t;
typedef bf16_t bf16x4 __attribute__((ext_vector_type(4)));
typedef bf16_t bf16x8 __attribute__((ext_vector_type(8)));
typedef float f32x4 __attribute__((ext_vector_type(4)));
typedef _Float16 f16_t;
typedef f16_t f16x8 __attribute__((ext_vector_type(8)));

// MFMA GEMM: out[m,n] = (dot(X[m,:], Wt[n,:]) + bias[n]) * scale
// X row-major [M][256], Wt row-major [256][256]. 128x64 tile, 4 waves (2x2).
__global__ __launch_bounds__(256) void proj_mfma_k(
    const float* __restrict__ X, const float* __restrict__ Wt,
    const float* __restrict__ bias, float* __restrict__ out,
    float scale, int M) {
  __shared__ bf16_t Xs[128 * 64];  // [m][c] swizzled
  __shared__ bf16_t Ws[64 * 64];   // [o][c] swizzled
  int m0 = blockIdx.x * 128;
  int o0 = blockIdx.y * 64;
  int tid = threadIdx.x;
  int lane = tid & 63, w = tid >> 6;
  int moff = (w & 1) * 64, ooff = (w >> 1) * 32;
  int l15 = lane & 15, l4 = lane >> 4;
  int srow = tid >> 1;             // X staging m-local 0..127
  int schalf = (tid & 1) * 32;     // X staging c-offset
  int wo_l = tid >> 2;             // W staging o-local
  int wcg = (tid & 3) * 16;        // W staging c-group

  f32x4 acc[4][2];
#pragma unroll
  for (int m = 0; m < 4; ++m)
#pragma unroll
    for (int n = 0; n < 2; ++n) acc[m][n] = (f32x4){0.f, 0.f, 0.f, 0.f};

  for (int c0 = 0; c0 < cC; c0 += 64) {
    {
      int mrow = min(m0 + srow, M - 1);
      const float4* xr = (const float4*)(X + (size_t)mrow * cC + c0 + schalf);
      int sw = (srow & 7) * 8;
#pragma unroll
      for (int i = 0; i < 4; ++i) {
        float4 a = xr[i * 2], b4 = xr[i * 2 + 1];
        bf16x8 v = {(bf16_t)a.x, (bf16_t)a.y, (bf16_t)a.z, (bf16_t)a.w,
                    (bf16_t)b4.x, (bf16_t)b4.y, (bf16_t)b4.z, (bf16_t)b4.w};
        *(bf16x8*)&Xs[srow * 64 + ((schalf + i * 8) ^ sw)] = v;
      }
    }
    {
      const float4* wr = (const float4*)(Wt + (size_t)(o0 + wo_l) * cC + c0 + wcg);
      float4 a = wr[0], b4 = wr[1], c4 = wr[2], d4 = wr[3];
      bf16x8 w0 = {(bf16_t)a.x, (bf16_t)a.y, (bf16_t)a.z, (bf16_t)a.w,
                   (bf16_t)b4.x, (bf16_t)b4.y, (bf16_t)b4.z, (bf16_t)b4.w};
      bf16x8 w1 = {(bf16_t)c4.x, (bf16_t)c4.y, (bf16_t)c4.z, (bf16_t)c4.w,
                   (bf16_t)d4.x, (bf16_t)d4.y, (bf16_t)d4.z, (bf16_t)d4.w};
      int sw = (wo_l & 7) * 8;
      *(bf16x8*)&Ws[wo_l * 64 + (wcg ^ sw)] = w0;
      *(bf16x8*)&Ws[wo_l * 64 + ((wcg + 8) ^ sw)] = w1;
    }
    __syncthreads();
#pragma unroll
    for (int s = 0; s < 2; ++s) {
      int c8 = s * 32 + l4 * 8;
      bf16x8 afr[4], bfr[2];
#pragma unroll
      for (int m = 0; m < 4; ++m) {
        int r = moff + m * 16 + l15;
        afr[m] = *(const bf16x8*)&Xs[r * 64 + (c8 ^ ((r & 7) * 8))];
      }
#pragma unroll
      for (int n = 0; n < 2; ++n) {
        int r = ooff + n * 16 + l15;
        bfr[n] = *(const bf16x8*)&Ws[r * 64 + (c8 ^ ((r & 7) * 8))];
      }
#pragma unroll
      for (int m = 0; m < 4; ++m)
#pragma unroll
        for (int n = 0; n < 2; ++n)
          acc[m][n] = __builtin_amdgcn_mfma_f32_16x16x32_bf16(
              afr[m], bfr[n], acc[m][n], 0, 0, 0);
    }
    __syncthreads();
  }

  float b0 = bias[o0 + ooff + l15];
  float b1 = bias[o0 + ooff + 16 + l15];
#pragma unroll
  for (int m = 0; m < 4; ++m) {
    int mr = m0 + moff + m * 16 + l4 * 4;
#pragma unroll
    for (int reg = 0; reg < 4; ++reg) {
      if (mr + reg < M) {
        out[(size_t)(mr + reg) * cC + o0 + ooff + l15] =
            (acc[m][0][reg] + b0) * scale;
        out[(size_t)(mr + reg) * cC + o0 + ooff + 16 + l15] =
            (acc[m][1][reg] + b1) * scale;
      }
    }
  }
}

// bf16-MFMA K/V projection, writing TRANSPOSED fp16 layout directly:
// outT[((b*8+head)*4096 + hw)*32 + d] = sum_c W[o,c]*X[b,c,hw] + bias[o].
__global__ __launch_bounds__(256) void proj_kv_mfma_k(
    const float* __restrict__ key, const float* __restrict__ value,
    const float* __restrict__ Wk, const float* __restrict__ bk,
    const float* __restrict__ Wv, const float* __restrict__ bv,
    f16_t* __restrict__ pkT, f16_t* __restrict__ pvT) {
  int z = blockIdx.z;
  int b = z >> 1;
  bool isv = z & 1;
  const float* X = (isv ? value : key) + (size_t)b * cC * cHW;
  const float* Wm = isv ? Wv : Wk;
  const float* bb = isv ? bv : bk;
  f16_t* outT = (isv ? pvT : pkT) + (size_t)b * cHEADS * cHW * cHD;
  int hw0 = blockIdx.x * 128;
  int o0 = blockIdx.y * 64;

  __shared__ bf16_t Xs[128 * 64];  // X^T tile [hw][c] swizzled
  __shared__ bf16_t Ws[64 * 64];   // W tile  [o][c] swizzled

  int tid = threadIdx.x;
  int lane = tid & 63, w = tid >> 6;
  int hwl = (w & 1) * 64 + lane;
  int cbase = (w >> 1) * 32;
  int wo_l = tid >> 2;
  int wcg = (tid & 3) * 16;
  int hwoff = (w & 1) * 64, ooff = (w >> 1) * 32;
  int l15 = lane & 15, l4 = lane >> 4;

  f32x4 acc[4][2];
#pragma unroll
  for (int m = 0; m < 4; ++m)
#pragma unroll
    for (int n = 0; n < 2; ++n) acc[m][n] = (f32x4){0.f, 0.f, 0.f, 0.f};

  for (int c0 = 0; c0 < cC; c0 += 64) {
    const float* xcol = X + (size_t)(c0 + cbase) * cHW + hw0 + hwl;
#pragma unroll
    for (int i = 0; i < 8; ++i) {
      float f0 = xcol[(size_t)(i * 4 + 0) * cHW];
      float f1 = xcol[(size_t)(i * 4 + 1) * cHW];
      float f2 = xcol[(size_t)(i * 4 + 2) * cHW];
      float f3 = xcol[(size_t)(i * 4 + 3) * cHW];
      bf16x4 v = {(bf16_t)f0, (bf16_t)f1, (bf16_t)f2, (bf16_t)f3};
      int c_l = cbase + i * 4;
      *(bf16x4*)&Xs[hwl * 64 + (c_l ^ ((hwl & 7) * 8))] = v;
    }
    {
      const float4* wrow = (const float4*)(Wm + (size_t)(o0 + wo_l) * cC + c0 + wcg);
      float4 a = wrow[0], b4 = wrow[1], c4 = wrow[2], d4 = wrow[3];
      bf16x8 w0 = {(bf16_t)a.x, (bf16_t)a.y, (bf16_t)a.z, (bf16_t)a.w,
                   (bf16_t)b4.x, (bf16_t)b4.y, (bf16_t)b4.z, (bf16_t)b4.w};
      bf16x8 w1 = {(bf16_t)c4.x, (bf16_t)c4.y, (bf16_t)c4.z, (bf16_t)c4.w,
                   (bf16_t)d4.x, (bf16_t)d4.y, (bf16_t)d4.z, (bf16_t)d4.w};
      int sw = (wo_l & 7) * 8;
      *(bf16x8*)&Ws[wo_l * 64 + (wcg ^ sw)] = w0;
      *(bf16x8*)&Ws[wo_l * 64 + ((wcg + 8) ^ sw)] = w1;
    }
    __syncthreads();
#pragma unroll
    for (int s = 0; s < 2; ++s) {
      int c8 = s * 32 + l4 * 8;
      bf16x8 afr[4], bfr[2];
#pragma unroll
      for (int m = 0; m < 4; ++m) {
        int r = hwoff + m * 16 + l15;
        afr[m] = *(const bf16x8*)&Xs[r * 64 + (c8 ^ ((r & 7) * 8))];
      }
#pragma unroll
      for (int n = 0; n < 2; ++n) {
        int r = ooff + n * 16 + l15;
        bfr[n] = *(const bf16x8*)&Ws[r * 64 + (c8 ^ ((r & 7) * 8))];
      }
#pragma unroll
      for (int m = 0; m < 4; ++m)
#pragma unroll
        for (int n = 0; n < 2; ++n)
          acc[m][n] = __builtin_amdgcn_mfma_f32_16x16x32_bf16(
              afr[m], bfr[n], acc[m][n], 0, 0, 0);
    }
    __syncthreads();
  }

  int head = (o0 + ooff) >> 5;
  f16_t* obase = outT + (size_t)head * cHW * cHD;
  float bias0 = bb[o0 + ooff + l15];
  float bias1 = bb[o0 + ooff + 16 + l15];
#pragma unroll
  for (int m = 0; m < 4; ++m) {
    int hwr = hwoff + m * 16 + l4 * 4;
#pragma unroll
    for (int reg = 0; reg < 4; ++reg) {
      size_t rowoff = (size_t)(hw0 + hwr + reg) * cHD;
      obase[rowoff + l15] = (f16_t)(acc[m][0][reg] + bias0);
      obase[rowoff + 16 + l15] = (f16_t)(acc[m][1][reg] + bias1);
    }
  }
}

// One wave per (b,q,head); no LDS, no barriers. Target <=64 VGPR -> 8 waves/SIMD.
// PV loads double-buffered one k-group ahead instead of full preload.
__global__ __launch_bounds__(256, 8) void attn_k(
    const float* __restrict__ pq, const f16_t* __restrict__ pkT,
    const f16_t* __restrict__ pvT, const float* __restrict__ pts,
    float* __restrict__ out) {
  int bid = blockIdx.x;
  int xcd = bid & 7;
  int t = bid >> 3;                 // 0..599
  int phase = (t >= cNQ) ? 1 : 0;
  int q = t - phase * cNQ;
  int g = xcd + 8 * phase;          // 0..15
  int b = g >> 1;
  int pair = g & 1;
  int lane = threadIdx.x & 63;
  int wid = threadIdx.x >> 6;
  int n = pair * 4 + wid;

  float x = pts[((size_t)b * cNQ + q) * 2 + 0];
  float y = pts[((size_t)b * cNQ + q) * 2 + 1];
  float y0f = fminf(fmaxf(floorf(y), 0.f), (float)(cH - 1));
  float x0f = fminf(fmaxf(floorf(x), 0.f), (float)(cW - 1));
  float wy = y - y0f, wx = x - x0f;
  int y0 = (int)y0f, y1 = min(y0 + 1, cH - 1);
  int x0 = (int)x0f, x1 = min(x0 + 1, cW - 1);

  const f16_t* kTb = pkT + (size_t)(b * cHEADS + n) * cHW * cHD;
  const f16_t* vTb = pvT + (size_t)(b * cHEADS + n) * cHW * cHD;

  // ---- QK logits: lane = position ----
  const f16x8* kr0 = (const f16x8*)(kTb + (size_t)(y0 * cW + lane) * cHD);
  const f16x8* kr1 = (const f16x8*)(kTb + (size_t)(y1 * cW + lane) * cHD);
  const f16x8* kc0 = (const f16x8*)(kTb + (size_t)(lane * cW + x0) * cHD);
  const f16x8* kc1 = (const f16x8*)(kTb + (size_t)(lane * cW + x1) * cHD);
  const float4* qb = (const float4*)(pq + ((size_t)b * cNQ + q) * cC + n * cHD);
  float wrow = 0.f, wcol = 0.f;
#pragma unroll
  for (int c = 0; c < 4; ++c) {
    f16x8 a0 = kr0[c], a1 = kr1[c], b0 = kc0[c], b1 = kc1[c];
    float4 q0 = qb[c * 2], q1 = qb[c * 2 + 1];
    float qs[8] = {q0.x, q0.y, q0.z, q0.w, q1.x, q1.y, q1.z, q1.w};
#pragma unroll
    for (int j = 0; j < 8; ++j) {
      float f0 = (float)a0[j], f1 = (float)a1[j];
      float h0 = (float)b0[j], h1 = (float)b1[j];
      wrow += qs[j] * (f0 + wy * (f1 - f0));
      wcol += qs[j] * (h0 + wx * (h1 - h0));
    }
  }

  // ---- softmax (unnormalized; divide at the end) ----
  float m = fmaxf(wrow, wcol);
#pragma unroll
  for (int s = 32; s > 0; s >>= 1) m = fmaxf(m, __shfl_xor(m, s, 64));
  float er = expf(wrow - m), ec = expf(wcol - m);
  float ssum = er + ec;
#pragma unroll
  for (int s = 32; s > 0; s >>= 1) ssum += __shfl_xor(ssum, s, 64);

  // ---- PV: lane = (pos-group g16, d-chunk ch of 8); dbuf one k ahead ----
  int g16 = lane >> 2, ch = lane & 3;
  const f16_t* vb0 = vTb + (size_t)(y0 * cW) * cHD + ch * 8;  // + p*cHD
  const f16_t* vb1 = vTb + (size_t)(y1 * cW) * cHD + ch * 8;
  const f16_t* cb0 = vTb + (size_t)x0 * cHD + ch * 8;         // + p*cW*cHD
  const f16_t* cb1 = vTb + (size_t)x1 * cHD + ch * 8;

  f16x8 r0a, r1a, c0a, c1a, r0b, r1b, c0b, c1b;
  {
    int p = g16 * 4;
    r0a = *(const f16x8*)(vb0 + (size_t)p * cHD);
    r1a = *(const f16x8*)(vb1 + (size_t)p * cHD);
    c0a = *(const f16x8*)(cb0 + (size_t)p * cW * cHD);
    c1a = *(const f16x8*)(cb1 + (size_t)p * cW * cHD);
  }
  float acc[8];
#pragma unroll
  for (int j = 0; j < 8; ++j) acc[j] = 0.f;
#pragma unroll
  for (int k = 0; k < 4; ++k) {
    if (k < 3) {
      int p = g16 * 4 + k + 1;
      r0b = *(const f16x8*)(vb0 + (size_t)p * cHD);
      r1b = *(const f16x8*)(vb1 + (size_t)p * cHD);
      c0b = *(const f16x8*)(cb0 + (size_t)p * cW * cHD);
      c1b = *(const f16x8*)(cb1 + (size_t)p * cW * cHD);
    }
    int p = g16 * 4 + k;
    float ar = __shfl(er, p, 64);
    float ac = __shfl(ec, p, 64);
#pragma unroll
    for (int j = 0; j < 8; ++j) {
      float r0 = (float)r0a[j], r1 = (float)r1a[j];
      float c0 = (float)c0a[j], c1 = (float)c1a[j];
      acc[j] += ar * (r0 + wy * (r1 - r0)) + ac * (c0 + wx * (c1 - c0));
    }
    r0a = r0b; r1a = r1b; c0a = c0b; c1a = c1b;
  }
#pragma unroll
  for (int s = 4; s <= 32; s <<= 1)
#pragma unroll
    for (int j = 0; j < 8; ++j) acc[j] += __shfl_xor(acc[j], s, 64);

  float inv = 1.f / ssum;
  if (lane < 4) {
    float* op = out + ((size_t)b * cNQ + q) * cC + n * cHD + ch * 8;
    float4 o0 = {acc[0] * inv, acc[1] * inv, acc[2] * inv, acc[3] * inv};
    float4 o1 = {acc[4] * inv, acc[5] * inv, acc[6] * inv, acc[7] * inv};
    *(float4*)op = o0;
    *(float4*)(op + 4) = o1;
  }
}

extern "C" void kernel_launch(void* const* d_in, const int* in_sizes, int n_in,
                              void* d_out, int out_size, void* d_ws, size_t ws_size,
                              hipStream_t stream) {
  const float* query = (const float*)d_in[0];
  const float* key   = (const float*)d_in[1];
  const float* value = (const float*)d_in[2];
  const float* pts   = (const float*)d_in[3];
  const float* Wq = (const float*)d_in[4];
  const float* bq = (const float*)d_in[5];
  const float* Wk = (const float*)d_in[6];
  const float* bk = (const float*)d_in[7];
  const float* Wv = (const float*)d_in[8];
  const float* bv = (const float*)d_in[9];
  const float* Wo = (const float*)d_in[10];
  const float* bo = (const float*)d_in[11];
  float* out = (float*)d_out;

  float* pq = (float*)d_ws;                           // 2400*256 f32
  f16_t* pkT = (f16_t*)(pq + (size_t)cM * cC);        // 8*8*4096*32 f16
  f16_t* pvT = pkT + (size_t)cB * cC * cHW;
  float* ao = (float*)(pvT + (size_t)cB * cC * cHW);  // 2400*256 f32

  proj_mfma_k<<<dim3((cM + 127) / 128, cC / 64), 256, 0, stream>>>(
      query, Wq, bq, pq, cSCALE, cM);
  proj_kv_mfma_k<<<dim3(cHW / 128, cC / 64, cB * 2), 256, 0, stream>>>(
      key, value, Wk, bk, Wv, bv, pkT, pvT);
  attn_k<<<cB * cNQ * 2, 256, 0, stream>>>(pq, pkT, pvT, pts, ao);
  proj_mfma_k<<<dim3((cM + 127) / 128, cC / 64), 256, 0, stream>>>(
      ao, Wo, bo, out, 1.0f, cM);
}

// Round 7
// 105.429 us; speedup vs baseline: 2.4514x; 2.4514x over previous
//
#include <hip/hip_runtime.h>
#include <hip/hip_bf16.h>
#include <math.h>

constexpr int cB = 8, cNQ = 300, cC = 256, cH = 64, cW = 64, cHEADS = 8, cHD = 32;
constexpr int cHW = cH * cW;
constexpr int cM = cB * cNQ;  // 2400
constexpr float cSCALE = 0.1767766952966369f; // 32^-0.5

typedef __bf16 bf16_t;
typedef bf16_t bf16x4 __attribute__((ext_vector_type(4)));
typedef bf16_t bf16x8 __attribute__((ext_vector_type(8)));
typedef float f32x4 __attribute__((ext_vector_type(4)));
typedef _Float16 f16_t;
typedef f16_t f16x8 __attribute__((ext_vector_type(8)));

// MFMA GEMM: out[m,n] = (dot(X[m,:], Wt[n,:]) + bias[n]) * scale
__global__ __launch_bounds__(256) void proj_mfma_k(
    const float* __restrict__ X, const float* __restrict__ Wt,
    const float* __restrict__ bias, float* __restrict__ out,
    float scale, int M) {
  __shared__ bf16_t Xs[128 * 64];
  __shared__ bf16_t Ws[64 * 64];
  int m0 = blockIdx.x * 128;
  int o0 = blockIdx.y * 64;
  int tid = threadIdx.x;
  int lane = tid & 63, w = tid >> 6;
  int moff = (w & 1) * 64, ooff = (w >> 1) * 32;
  int l15 = lane & 15, l4 = lane >> 4;
  int srow = tid >> 1;
  int schalf = (tid & 1) * 32;
  int wo_l = tid >> 2;
  int wcg = (tid & 3) * 16;

  f32x4 acc[4][2];
#pragma unroll
  for (int m = 0; m < 4; ++m)
#pragma unroll
    for (int n = 0; n < 2; ++n) acc[m][n] = (f32x4){0.f, 0.f, 0.f, 0.f};

  for (int c0 = 0; c0 < cC; c0 += 64) {
    {
      int mrow = min(m0 + srow, M - 1);
      const float4* xr = (const float4*)(X + (size_t)mrow * cC + c0 + schalf);
      int sw = (srow & 7) * 8;
#pragma unroll
      for (int i = 0; i < 4; ++i) {
        float4 a = xr[i * 2], b4 = xr[i * 2 + 1];
        bf16x8 v = {(bf16_t)a.x, (bf16_t)a.y, (bf16_t)a.z, (bf16_t)a.w,
                    (bf16_t)b4.x, (bf16_t)b4.y, (bf16_t)b4.z, (bf16_t)b4.w};
        *(bf16x8*)&Xs[srow * 64 + ((schalf + i * 8) ^ sw)] = v;
      }
    }
    {
      const float4* wr = (const float4*)(Wt + (size_t)(o0 + wo_l) * cC + c0 + wcg);
      float4 a = wr[0], b4 = wr[1], c4 = wr[2], d4 = wr[3];
      bf16x8 w0 = {(bf16_t)a.x, (bf16_t)a.y, (bf16_t)a.z, (bf16_t)a.w,
                   (bf16_t)b4.x, (bf16_t)b4.y, (bf16_t)b4.z, (bf16_t)b4.w};
      bf16x8 w1 = {(bf16_t)c4.x, (bf16_t)c4.y, (bf16_t)c4.z, (bf16_t)c4.w,
                   (bf16_t)d4.x, (bf16_t)d4.y, (bf16_t)d4.z, (bf16_t)d4.w};
      int sw = (wo_l & 7) * 8;
      *(bf16x8*)&Ws[wo_l * 64 + (wcg ^ sw)] = w0;
      *(bf16x8*)&Ws[wo_l * 64 + ((wcg + 8) ^ sw)] = w1;
    }
    __syncthreads();
#pragma unroll
    for (int s = 0; s < 2; ++s) {
      int c8 = s * 32 + l4 * 8;
      bf16x8 afr[4], bfr[2];
#pragma unroll
      for (int m = 0; m < 4; ++m) {
        int r = moff + m * 16 + l15;
        afr[m] = *(const bf16x8*)&Xs[r * 64 + (c8 ^ ((r & 7) * 8))];
      }
#pragma unroll
      for (int n = 0; n < 2; ++n) {
        int r = ooff + n * 16 + l15;
        bfr[n] = *(const bf16x8*)&Ws[r * 64 + (c8 ^ ((r & 7) * 8))];
      }
#pragma unroll
      for (int m = 0; m < 4; ++m)
#pragma unroll
        for (int n = 0; n < 2; ++n)
          acc[m][n] = __builtin_amdgcn_mfma_f32_16x16x32_bf16(
              afr[m], bfr[n], acc[m][n], 0, 0, 0);
    }
    __syncthreads();
  }

  float b0 = bias[o0 + ooff + l15];
  float b1 = bias[o0 + ooff + 16 + l15];
#pragma unroll
  for (int m = 0; m < 4; ++m) {
    int mr = m0 + moff + m * 16 + l4 * 4;
#pragma unroll
    for (int reg = 0; reg < 4; ++reg) {
      if (mr + reg < M) {
        out[(size_t)(mr + reg) * cC + o0 + ooff + l15] =
            (acc[m][0][reg] + b0) * scale;
        out[(size_t)(mr + reg) * cC + o0 + ooff + 16 + l15] =
            (acc[m][1][reg] + b1) * scale;
      }
    }
  }
}

// bf16-MFMA K/V projection. Writes TWO fp16 layouts:
//  row-major spatial: outT [((b*8+h)*4096 + y*64+x)*32 + d]
//  col-major spatial: outTc[((b*8+h)*4096 + x*64+y)*32 + d]
__global__ __launch_bounds__(256) void proj_kv_mfma_k(
    const float* __restrict__ key, const float* __restrict__ value,
    const float* __restrict__ Wk, const float* __restrict__ bk,
    const float* __restrict__ Wv, const float* __restrict__ bv,
    f16_t* __restrict__ pkT, f16_t* __restrict__ pvT,
    f16_t* __restrict__ pkTc, f16_t* __restrict__ pvTc) {
  int z = blockIdx.z;
  int b = z >> 1;
  bool isv = z & 1;
  const float* X = (isv ? value : key) + (size_t)b * cC * cHW;
  const float* Wm = isv ? Wv : Wk;
  const float* bb = isv ? bv : bk;
  f16_t* outT = (isv ? pvT : pkT) + (size_t)b * cHEADS * cHW * cHD;
  f16_t* outTc = (isv ? pvTc : pkTc) + (size_t)b * cHEADS * cHW * cHD;
  int hw0 = blockIdx.x * 128;
  int o0 = blockIdx.y * 64;

  __shared__ bf16_t Xs[128 * 64];
  __shared__ bf16_t Ws[64 * 64];

  int tid = threadIdx.x;
  int lane = tid & 63, w = tid >> 6;
  int hwl = (w & 1) * 64 + lane;
  int cbase = (w >> 1) * 32;
  int wo_l = tid >> 2;
  int wcg = (tid & 3) * 16;
  int hwoff = (w & 1) * 64, ooff = (w >> 1) * 32;
  int l15 = lane & 15, l4 = lane >> 4;

  f32x4 acc[4][2];
#pragma unroll
  for (int m = 0; m < 4; ++m)
#pragma unroll
    for (int n = 0; n < 2; ++n) acc[m][n] = (f32x4){0.f, 0.f, 0.f, 0.f};

  for (int c0 = 0; c0 < cC; c0 += 64) {
    const float* xcol = X + (size_t)(c0 + cbase) * cHW + hw0 + hwl;
#pragma unroll
    for (int i = 0; i < 8; ++i) {
      float f0 = xcol[(size_t)(i * 4 + 0) * cHW];
      float f1 = xcol[(size_t)(i * 4 + 1) * cHW];
      float f2 = xcol[(size_t)(i * 4 + 2) * cHW];
      float f3 = xcol[(size_t)(i * 4 + 3) * cHW];
      bf16x4 v = {(bf16_t)f0, (bf16_t)f1, (bf16_t)f2, (bf16_t)f3};
      int c_l = cbase + i * 4;
      *(bf16x4*)&Xs[hwl * 64 + (c_l ^ ((hwl & 7) * 8))] = v;
    }
    {
      const float4* wrow = (const float4*)(Wm + (size_t)(o0 + wo_l) * cC + c0 + wcg);
      float4 a = wrow[0], b4 = wrow[1], c4 = wrow[2], d4 = wrow[3];
      bf16x8 w0 = {(bf16_t)a.x, (bf16_t)a.y, (bf16_t)a.z, (bf16_t)a.w,
                   (bf16_t)b4.x, (bf16_t)b4.y, (bf16_t)b4.z, (bf16_t)b4.w};
      bf16x8 w1 = {(bf16_t)c4.x, (bf16_t)c4.y, (bf16_t)c4.z, (bf16_t)c4.w,
                   (bf16_t)d4.x, (bf16_t)d4.y, (bf16_t)d4.z, (bf16_t)d4.w};
      int sw = (wo_l & 7) * 8;
      *(bf16x8*)&Ws[wo_l * 64 + (wcg ^ sw)] = w0;
      *(bf16x8*)&Ws[wo_l * 64 + ((wcg + 8) ^ sw)] = w1;
    }
    __syncthreads();
#pragma unroll
    for (int s = 0; s < 2; ++s) {
      int c8 = s * 32 + l4 * 8;
      bf16x8 afr[4], bfr[2];
#pragma unroll
      for (int m = 0; m < 4; ++m) {
        int r = hwoff + m * 16 + l15;
        afr[m] = *(const bf16x8*)&Xs[r * 64 + (c8 ^ ((r & 7) * 8))];
      }
#pragma unroll
      for (int n = 0; n < 2; ++n) {
        int r = ooff + n * 16 + l15;
        bfr[n] = *(const bf16x8*)&Ws[r * 64 + (c8 ^ ((r & 7) * 8))];
      }
#pragma unroll
      for (int m = 0; m < 4; ++m)
#pragma unroll
        for (int n = 0; n < 2; ++n)
          acc[m][n] = __builtin_amdgcn_mfma_f32_16x16x32_bf16(
              afr[m], bfr[n], acc[m][n], 0, 0, 0);
    }
    __syncthreads();
  }

  int head = (o0 + ooff) >> 5;
  f16_t* obase = outT + (size_t)head * cHW * cHD;
  f16_t* obaseC = outTc + (size_t)head * cHW * cHD;
  float bias0 = bb[o0 + ooff + l15];
  float bias1 = bb[o0 + ooff + 16 + l15];
#pragma unroll
  for (int m = 0; m < 4; ++m) {
    int hwr = hwoff + m * 16 + l4 * 4;
#pragma unroll
    for (int reg = 0; reg < 4; ++reg) {
      int hw = hw0 + hwr + reg;
      f16_t v0 = (f16_t)(acc[m][0][reg] + bias0);
      f16_t v1 = (f16_t)(acc[m][1][reg] + bias1);
      size_t rowoff = (size_t)hw * cHD;
      obase[rowoff + l15] = v0;
      obase[rowoff + 16 + l15] = v1;
      int yy = hw >> 6, xx = hw & 63;
      size_t rowoffC = (size_t)(xx * cH + yy) * cHD;
      obaseC[rowoffC + l15] = v0;
      obaseC[rowoffC + 16 + l15] = v1;
    }
  }
}

// One wave per (b,q,head); no LDS, no barriers. Full V-preload (round-5 proven).
// Block = 4 waves = 2 heads x 2 queries. 32 phase groups (b, headpair):
// per-XCD per-phase working set = 2 heads x (K+V) x 2 layouts = 2 MB << 4 MB L2.
__global__ __launch_bounds__(256) void attn_k(
    const float* __restrict__ pq, const f16_t* __restrict__ pkT,
    const f16_t* __restrict__ pkTc, const f16_t* __restrict__ pvT,
    const f16_t* __restrict__ pvTc, const float* __restrict__ pts,
    float* __restrict__ out) {
  int bid = blockIdx.x;
  int xcd = bid & 7;
  int t = bid >> 3;                 // 0..599
  int phase = t / 150;              // 0..3
  int idx = t - phase * 150;        // 0..149
  int g = xcd + 8 * phase;          // 0..31
  int b = g >> 2;
  int hp = g & 3;
  int lane = threadIdx.x & 63;
  int wid = threadIdx.x >> 6;
  int n = hp * 2 + (wid & 1);
  int q = idx * 2 + (wid >> 1);

  float x = pts[((size_t)b * cNQ + q) * 2 + 0];
  float y = pts[((size_t)b * cNQ + q) * 2 + 1];
  float y0f = fminf(fmaxf(floorf(y), 0.f), (float)(cH - 1));
  float x0f = fminf(fmaxf(floorf(x), 0.f), (float)(cW - 1));
  float wy = y - y0f, wx = x - x0f;
  int y0 = (int)y0f, y1 = min(y0 + 1, cH - 1);
  int x0 = (int)x0f, x1 = min(x0 + 1, cW - 1);

  size_t hoff = (size_t)(b * cHEADS + n) * cHW * cHD;
  const f16_t* kTb = pkT + hoff;
  const f16_t* kTcb = pkTc + hoff;
  const f16_t* vTb = pvT + hoff;
  const f16_t* vTcb = pvTc + hoff;

  // ---- early-issue PV loads (independent of QK/softmax) ----
  int g16 = lane >> 2, ch = lane & 3;
  f16x8 vr0[4], vr1[4], vc0[4], vc1[4];
#pragma unroll
  for (int k = 0; k < 4; ++k) {
    int p = g16 * 4 + k;
    vr0[k] = *(const f16x8*)(vTb + (size_t)(y0 * cW + p) * cHD + ch * 8);
    vr1[k] = *(const f16x8*)(vTb + (size_t)(y1 * cW + p) * cHD + ch * 8);
    vc0[k] = *(const f16x8*)(vTcb + (size_t)(x0 * cH + p) * cHD + ch * 8);
    vc1[k] = *(const f16x8*)(vTcb + (size_t)(x1 * cH + p) * cHD + ch * 8);
  }

  // ---- QK logits: lane = position; all four samples lane-contiguous ----
  const f16x8* kr0 = (const f16x8*)(kTb + (size_t)(y0 * cW + lane) * cHD);
  const f16x8* kr1 = (const f16x8*)(kTb + (size_t)(y1 * cW + lane) * cHD);
  const f16x8* kc0 = (const f16x8*)(kTcb + (size_t)(x0 * cH + lane) * cHD);
  const f16x8* kc1 = (const f16x8*)(kTcb + (size_t)(x1 * cH + lane) * cHD);
  const float4* qb = (const float4*)(pq + ((size_t)b * cNQ + q) * cC + n * cHD);
  float wr0 = 0.f, wr1 = 0.f, wc0 = 0.f, wc1 = 0.f;  // dual chains
#pragma unroll
  for (int c = 0; c < 4; ++c) {
    f16x8 a0 = kr0[c], a1 = kr1[c], b0 = kc0[c], b1 = kc1[c];
    float4 q0 = qb[c * 2], q1 = qb[c * 2 + 1];
    float qs[8] = {q0.x, q0.y, q0.z, q0.w, q1.x, q1.y, q1.z, q1.w};
#pragma unroll
    for (int j = 0; j < 8; ++j) {
      float f0 = (float)a0[j], f1 = (float)a1[j];
      float h0 = (float)b0[j], h1 = (float)b1[j];
      if (j & 1) {
        wr1 += qs[j] * (f0 + wy * (f1 - f0));
        wc1 += qs[j] * (h0 + wx * (h1 - h0));
      } else {
        wr0 += qs[j] * (f0 + wy * (f1 - f0));
        wc0 += qs[j] * (h0 + wx * (h1 - h0));
      }
    }
  }
  float wrow = wr0 + wr1, wcol = wc0 + wc1;

  // ---- softmax (unnormalized; divide at the end) ----
  float m = fmaxf(wrow, wcol);
#pragma unroll
  for (int s = 32; s > 0; s >>= 1) m = fmaxf(m, __shfl_xor(m, s, 64));
  float er = expf(wrow - m), ec = expf(wcol - m);
  float ssum = er + ec;
#pragma unroll
  for (int s = 32; s > 0; s >>= 1) ssum += __shfl_xor(ssum, s, 64);

  // ---- PV: lane = (pos-group g16, d-chunk ch of 8); weights via shfl ----
  float acc[8];
#pragma unroll
  for (int j = 0; j < 8; ++j) acc[j] = 0.f;
#pragma unroll
  for (int k = 0; k < 4; ++k) {
    int p = g16 * 4 + k;
    float ar = __shfl(er, p, 64);
    float ac = __shfl(ec, p, 64);
#pragma unroll
    for (int j = 0; j < 8; ++j) {
      float r0 = (float)vr0[k][j], r1 = (float)vr1[k][j];
      float c0 = (float)vc0[k][j], c1 = (float)vc1[k][j];
      acc[j] += ar * (r0 + wy * (r1 - r0)) + ac * (c0 + wx * (c1 - c0));
    }
  }
#pragma unroll
  for (int s = 4; s <= 32; s <<= 1)
#pragma unroll
    for (int j = 0; j < 8; ++j) acc[j] += __shfl_xor(acc[j], s, 64);

  float inv = 1.f / ssum;
  if (lane < 4) {
    float* op = out + ((size_t)b * cNQ + q) * cC + n * cHD + ch * 8;
    float4 o0 = {acc[0] * inv, acc[1] * inv, acc[2] * inv, acc[3] * inv};
    float4 o1 = {acc[4] * inv, acc[5] * inv, acc[6] * inv, acc[7] * inv};
    *(float4*)op = o0;
    *(float4*)(op + 4) = o1;
  }
}

extern "C" void kernel_launch(void* const* d_in, const int* in_sizes, int n_in,
                              void* d_out, int out_size, void* d_ws, size_t ws_size,
                              hipStream_t stream) {
  const float* query = (const float*)d_in[0];
  const float* key   = (const float*)d_in[1];
  const float* value = (const float*)d_in[2];
  const float* pts   = (const float*)d_in[3];
  const float* Wq = (const float*)d_in[4];
  const float* bq = (const float*)d_in[5];
  const float* Wk = (const float*)d_in[6];
  const float* bk = (const float*)d_in[7];
  const float* Wv = (const float*)d_in[8];
  const float* bv = (const float*)d_in[9];
  const float* Wo = (const float*)d_in[10];
  const float* bo = (const float*)d_in[11];
  float* out = (float*)d_out;

  const size_t kvsz = (size_t)cB * cC * cHW;          // halves per layout
  float* pq = (float*)d_ws;                           // 2400*256 f32
  f16_t* pkT = (f16_t*)(pq + (size_t)cM * cC);
  f16_t* pvT = pkT + kvsz;
  f16_t* pkTc = pvT + kvsz;
  f16_t* pvTc = pkTc + kvsz;
  float* ao = (float*)(pvTc + kvsz);                  // 2400*256 f32

  proj_mfma_k<<<dim3((cM + 127) / 128, cC / 64), 256, 0, stream>>>(
      query, Wq, bq, pq, cSCALE, cM);
  proj_kv_mfma_k<<<dim3(cHW / 128, cC / 64, cB * 2), 256, 0, stream>>>(
      key, value, Wk, bk, Wv, bv, pkT, pvT, pkTc, pvTc);
  attn_k<<<cB * cNQ * 2, 256, 0, stream>>>(pq, pkT, pkTc, pvT, pvTc, pts, ao);
  proj_mfma_k<<<dim3((cM + 127) / 128, cC / 64), 256, 0, stream>>>(
      ao, Wo, bo, out, 1.0f, cM);
}